// Round 11
// baseline (294.210 us; speedup 1.0000x reference)
//
#include <hip/hip_runtime.h>
#include <hip/hip_bf16.h>

#define T_TOK 2048
#define H_DIM 1024
#define E_N   8
#define I_DIM 2048

#define NT_MAX 40         // sum ceil(cnt_e/128) <= 4096/128 + 7 = 39
#define MAX_SLOTS 5120    // 40 tiles * 128 rows

typedef unsigned short u16;
typedef unsigned int   u32;
typedef __bf16 bf16_t;
typedef bf16_t bf16x8 __attribute__((ext_vector_type(8)));
typedef u16    u16x8  __attribute__((ext_vector_type(8)));
typedef float  f32x16 __attribute__((ext_vector_type(16)));

#define MFMA32 __builtin_amdgcn_mfma_f32_32x32x16_bf16

__device__ __forceinline__ u16 bfbits(float f) {
    bf16_t b = (bf16_t)f;
    return __builtin_bit_cast(u16, b);
}
__device__ __forceinline__ float bf2f(u16 u) {
    u32 x = ((u32)u) << 16;
    return __builtin_bit_cast(float, x);
}

__device__ __forceinline__ void gload_lds16(const void* g, void* l) {
    __builtin_amdgcn_global_load_lds(
        (const __attribute__((address_space(1))) void*)g,
        (__attribute__((address_space(3))) void*)l, 16, 0, 0);
}

// B LDS tile: col n (0..127), k-slot kb (0..7); XOR keeps reads/writes ~4-way
__device__ __forceinline__ int tile_off(int n, int kb) {
    return n * 64 + ((kb ^ ((n >> 1) & 7)) << 3);
}
// A LDS tile (linear gload_lds dest, source k-group pre-XOR'd): row, kslot
__device__ __forceinline__ int a_off(int row, int kslot) {
    return row * 64 + ((kslot ^ (row & 7)) << 3);
}

// ---------------- router: 4 tokens/block
__global__ __launch_bounds__(256) void router_k(
    const float* __restrict__ x, const float* __restrict__ rw,
    int* __restrict__ cnt, int* __restrict__ tok, float* __restrict__ wts,
    u16* __restrict__ xbf)
{
    int wid = threadIdx.x >> 6, lane = threadIdx.x & 63;
    int t = blockIdx.x * 4 + wid;
    const float* xr = x + (size_t)t * H_DIM;
    u16* xbr = xbf + (size_t)t * H_DIM;

    float acc[E_N];
#pragma unroll
    for (int e = 0; e < E_N; e++) acc[e] = 0.f;
    for (int j = 0; j < H_DIM / 64; j++) {
        float xv = xr[lane + 64 * j];
        xbr[lane + 64 * j] = bfbits(xv);
#pragma unroll
        for (int e = 0; e < E_N; e++)
            acc[e] += xv * rw[e * H_DIM + lane + 64 * j];
    }
#pragma unroll
    for (int e = 0; e < E_N; e++) {
        float v = acc[e];
        for (int off = 32; off; off >>= 1) v += __shfl_xor(v, off);
        acc[e] = v;
    }
    if (lane == 0) {
        int i0 = 0; float m0 = acc[0];
#pragma unroll
        for (int e = 1; e < E_N; e++) if (acc[e] > m0) { m0 = acc[e]; i0 = e; }
        int i1 = -1; float m1 = -INFINITY;
#pragma unroll
        for (int e = 0; e < E_N; e++) if (e != i0 && acc[e] > m1) { m1 = acc[e]; i1 = e; }
        float w0 = 1.f / (1.f + expf(m1 - m0));
        float w1 = 1.f - w0;
        int p0 = atomicAdd(&cnt[i0], 1);
        tok[i0 * T_TOK + p0] = t; wts[i0 * T_TOK + p0] = w0;
        int p1 = atomicAdd(&cnt[i1], 1);
        tok[i1 * T_TOK + p1] = t; wts[i1 * T_TOK + p1] = w1;
    }
}

// ---------------- prefix + padded tile map (BM=128)
__global__ void prefix_k(const int* __restrict__ cnt, int* __restrict__ offs_pad,
                         int* __restrict__ tile_e, int* __restrict__ tile_row0,
                         int* __restrict__ ntiles)
{
    if (threadIdx.x == 0) {
        int s = 0, nt = 0;
        for (int e = 0; e < E_N; e++) {
            offs_pad[e] = s;
            int c = cnt[e];
            int t = (c + 127) >> 7;
            for (int i = 0; i < t; i++) { tile_e[nt] = e; tile_row0[nt] = i * 128; nt++; }
            s += t * 128;
        }
        offs_pad[E_N] = s;
        *ntiles = nt;
    }
}

// ---------------- single-matrix grouped GEMM x@W, fused fp32->bf16 cvt.
// tile 128x128, BK=64, 4 waves (2Mx2N), wave tile 64x64, 32x32x16 MFMA.
// MODE 0: write raw result to gbuf. MODE 1: read gbuf, act = silu(g)*u (masked).
template <int MODE>
__global__ __launch_bounds__(256, 2) void gu_k(
    const u16* __restrict__ xbf, const float* __restrict__ W,
    const int* __restrict__ cnt, const int* __restrict__ offs_pad,
    const int* __restrict__ tile_e, const int* __restrict__ tile_row0,
    const int* __restrict__ ntiles, const int* __restrict__ tok,
    u16* __restrict__ gbuf, u16* __restrict__ act)
{
    int q = gridDim.x >> 3;
    int phys = blockIdx.x;
    int logical = (phys & 7) * q + (phys >> 3);
    int tb = logical % NT_MAX;
    int p  = logical / NT_MAX;             // n-panel 0..15
    if (tb >= *ntiles) return;
    int e = tile_e[tb], row0 = tile_row0[tb];
    int cntE = cnt[e];
    int slot0 = offs_pad[e] + row0;
    int n0 = p * 128;

    __shared__ u16 AS[2][8192], BS[2][8192];   // 64 KB -> 2 blocks/CU

    int tid = threadIdx.x;
    int lane = tid & 63, wid = tid >> 6;       // 4 waves
    int wm = wid >> 1, wn = wid & 1;
    int l31 = lane & 31, lh = lane >> 5;

    // A staging: wave wid stages rows wid*32 .. wid*32+31 (4 gload_lds)
    const u16* asrc[4];
#pragma unroll
    for (int i = 0; i < 4; i++) {
        int row = (wid * 4 + i) * 8 + (lane >> 3);
        int rc = (row0 + row < cntE) ? (row0 + row) : (cntE - 1);
        asrc[i] = xbf + (size_t)tok[e * T_TOK + rc] * H_DIM
                  + (((lane & 7) ^ ((lane >> 3) & 7)) << 3);
    }
    int s0 = wid * 2048;

    // B staging: thread owns column bn, k-half khalf (32 k's)
    int bn = tid & 127;
    int khalf = tid >> 7;                  // 0..1
    const float* wsrc = W + (size_t)e * H_DIM * I_DIM + n0 + bn;

    float v0[32], v1[32];

#define BLOAD(vs, t) { \
    _Pragma("unroll") \
    for (int j = 0; j < 32; j++) \
        vs[j] = wsrc[(size_t)((t) * 64 + khalf * 32 + j) * I_DIM]; }

#define BWRITE(vs, nbuf) { \
    _Pragma("unroll") \
    for (int jb = 0; jb < 4; jb++) { \
        u16x8 pk; \
        _Pragma("unroll") \
        for (int jj = 0; jj < 8; jj++) pk[jj] = bfbits(vs[jb * 8 + jj]); \
        *reinterpret_cast<u16x8*>(&BS[nbuf][tile_off(bn, khalf * 4 + jb)]) = pk; } }

#define ASTAGE(nbuf, t) { \
    _Pragma("unroll") \
    for (int i = 0; i < 4; i++) \
        gload_lds16(asrc[i] + (size_t)(t) * 64, &AS[nbuf][s0 + i * 512]); }

    f32x16 acc[2][2];
#pragma unroll
    for (int a = 0; a < 2; a++)
#pragma unroll
        for (int b = 0; b < 2; b++) acc[a][b] = (f32x16)0.f;

#define CLUSTER(bufi) { \
    _Pragma("unroll") \
    for (int ks = 0; ks < 4; ks++) { \
        bf16x8 af[2], bfr[2]; \
        _Pragma("unroll") \
        for (int mf = 0; mf < 2; mf++) \
            af[mf] = *reinterpret_cast<const bf16x8*>(&AS[bufi][a_off(wm * 64 + mf * 32 + l31, ks * 2 + lh)]); \
        _Pragma("unroll") \
        for (int nf = 0; nf < 2; nf++) \
            bfr[nf] = *reinterpret_cast<const bf16x8*>(&BS[bufi][tile_off(wn * 64 + nf * 32 + l31, ks * 2 + lh)]); \
        _Pragma("unroll") \
        for (int mf = 0; mf < 2; mf++) \
            _Pragma("unroll") \
            for (int nf = 0; nf < 2; nf++) \
                acc[mf][nf] = MFMA32(af[mf], bfr[nf], acc[mf][nf], 0, 0, 0); } }

    // prologue (pinned order, one full drain)
    ASTAGE(0, 0);
    __builtin_amdgcn_sched_barrier(0);
    BLOAD(v0, 0);
    __builtin_amdgcn_sched_barrier(0);
    BLOAD(v1, 1);
    __builtin_amdgcn_sched_barrier(0);
    BWRITE(v0, 0);
    __builtin_amdgcn_sched_barrier(0);
    asm volatile("s_waitcnt vmcnt(0) lgkmcnt(0)" ::: "memory");
    __builtin_amdgcn_s_barrier();
    __builtin_amdgcn_sched_barrier(0);

    for (int t2 = 0; t2 < 16; t2 += 2) {
        // even iter t=t2 (buf0): consume buf0; write t+1 -> buf1; load t+2 -> v0
        if (t2 + 1 < 16) ASTAGE(1, t2 + 1);
        CLUSTER(0);
        __builtin_amdgcn_sched_barrier(0);
        if (t2 + 1 < 16) BWRITE(v1, 1);
        __builtin_amdgcn_sched_barrier(0);
        if (t2 + 2 < 16) {
            BLOAD(v0, t2 + 2);
            __builtin_amdgcn_sched_barrier(0);
            asm volatile("s_waitcnt vmcnt(32) lgkmcnt(0)" ::: "memory");
        } else {
            asm volatile("s_waitcnt vmcnt(0) lgkmcnt(0)" ::: "memory");
        }
        __builtin_amdgcn_s_barrier();
        __builtin_amdgcn_sched_barrier(0);

        // odd iter t=t2+1 (buf1)
        {
            int t = t2 + 1;
            if (t + 1 < 16) ASTAGE(0, t + 1);
            CLUSTER(1);
            __builtin_amdgcn_sched_barrier(0);
            if (t + 1 < 16) {
                BWRITE(v0, 0);
                __builtin_amdgcn_sched_barrier(0);
                if (t + 2 < 16) {
                    BLOAD(v1, t + 2);
                    __builtin_amdgcn_sched_barrier(0);
                    asm volatile("s_waitcnt vmcnt(32) lgkmcnt(0)" ::: "memory");
                } else {
                    asm volatile("s_waitcnt vmcnt(0) lgkmcnt(0)" ::: "memory");
                }
                __builtin_amdgcn_s_barrier();
                __builtin_amdgcn_sched_barrier(0);
            }
        }
    }
#undef BLOAD
#undef BWRITE
#undef ASTAGE
#undef CLUSTER

    // epilogue: C layout (32x32): col = lane&31, row = (r&3) + 8*(r>>2) + 4*(lane>>5)
#pragma unroll
    for (int mf = 0; mf < 2; mf++)
#pragma unroll
        for (int nf = 0; nf < 2; nf++) {
            int col = n0 + wn * 64 + nf * 32 + l31;
#pragma unroll
            for (int r = 0; r < 16; r++) {
                int rl = wm * 64 + mf * 32 + (r & 3) + 8 * (r >> 2) + 4 * lh;
                size_t idx = (size_t)(slot0 + rl) * I_DIM + col;
                if constexpr (MODE == 0) {
                    gbuf[idx] = bfbits(acc[mf][nf][r]);
                } else {
                    bool valid = (row0 + rl) < cntE;
                    float g = bf2f(gbuf[idx]);
                    float u = acc[mf][nf][r];
                    float a = valid ? (g / (1.f + expf(-g))) * u : 0.f;
                    act[idx] = bfbits(a);
                }
            }
        }
}

// ---------------- down grouped GEMM: out[t] += w * (act @ w_down[e])
// same structure; K split in 2 halves of 1024; 32x32x16; atomicAdd epilogue
__global__ __launch_bounds__(256, 2) void down_k(
    const u16* __restrict__ act, const float* __restrict__ wd,
    const int* __restrict__ cnt, const int* __restrict__ offs_pad,
    const int* __restrict__ tile_e, const int* __restrict__ tile_row0,
    const int* __restrict__ ntiles, const int* __restrict__ tok,
    const float* __restrict__ wts, float* __restrict__ out)
{
    int q = gridDim.x >> 3;
    int phys = blockIdx.x;
    int logical = (phys & 7) * q + (phys >> 3);
    int tb = logical % NT_MAX;
    int rest = logical / NT_MAX;
    int p  = rest & 7;                     // h-panel 0..7
    int kh = rest >> 3;                    // K half
    if (tb >= *ntiles) return;
    int e = tile_e[tb], row0 = tile_row0[tb];
    int cntE = cnt[e];
    int slot0 = offs_pad[e] + row0;
    int h0 = p * 128;

    __shared__ u16 AS[2][8192], BS[2][8192];

    int tid = threadIdx.x;
    int lane = tid & 63, wid = tid >> 6;
    int wm = wid >> 1, wn = wid & 1;
    int l31 = lane & 31, lh = lane >> 5;

    const u16* asrc[4];
#pragma unroll
    for (int i = 0; i < 4; i++) {
        int row = (wid * 4 + i) * 8 + (lane >> 3);
        asrc[i] = act + (size_t)(slot0 + row) * I_DIM + kh * 1024
                  + (((lane & 7) ^ ((lane >> 3) & 7)) << 3);
    }
    int s0 = wid * 2048;

    int bn = tid & 127;
    int khalf = tid >> 7;
    const float* dsrc = wd + ((size_t)e * I_DIM + kh * 1024) * H_DIM + h0 + bn;

    float v0[32], v1[32];

#define BLOAD(vs, t) { \
    _Pragma("unroll") \
    for (int j = 0; j < 32; j++) \
        vs[j] = dsrc[(size_t)((t) * 64 + khalf * 32 + j) * H_DIM]; }

#define BWRITE(vs, nbuf) { \
    _Pragma("unroll") \
    for (int jb = 0; jb < 4; jb++) { \
        u16x8 pk; \
        _Pragma("unroll") \
        for (int jj = 0; jj < 8; jj++) pk[jj] = bfbits(vs[jb * 8 + jj]); \
        *reinterpret_cast<u16x8*>(&BS[nbuf][tile_off(bn, khalf * 4 + jb)]) = pk; } }

#define ASTAGE(nbuf, t) { \
    _Pragma("unroll") \
    for (int i = 0; i < 4; i++) \
        gload_lds16(asrc[i] + (size_t)(t) * 64, &AS[nbuf][s0 + i * 512]); }

    f32x16 acc[2][2];
#pragma unroll
    for (int a = 0; a < 2; a++)
#pragma unroll
        for (int b = 0; b < 2; b++) acc[a][b] = (f32x16)0.f;

#define CLUSTER(bufi) { \
    _Pragma("unroll") \
    for (int ks = 0; ks < 4; ks++) { \
        bf16x8 af[2], bfr[2]; \
        _Pragma("unroll") \
        for (int mf = 0; mf < 2; mf++) \
            af[mf] = *reinterpret_cast<const bf16x8*>(&AS[bufi][a_off(wm * 64 + mf * 32 + l31, ks * 2 + lh)]); \
        _Pragma("unroll") \
        for (int nf = 0; nf < 2; nf++) \
            bfr[nf] = *reinterpret_cast<const bf16x8*>(&BS[bufi][tile_off(wn * 64 + nf * 32 + l31, ks * 2 + lh)]); \
        _Pragma("unroll") \
        for (int mf = 0; mf < 2; mf++) \
            _Pragma("unroll") \
            for (int nf = 0; nf < 2; nf++) \
                acc[mf][nf] = MFMA32(af[mf], bfr[nf], acc[mf][nf], 0, 0, 0); } }

    ASTAGE(0, 0);
    __builtin_amdgcn_sched_barrier(0);
    BLOAD(v0, 0);
    __builtin_amdgcn_sched_barrier(0);
    BLOAD(v1, 1);
    __builtin_amdgcn_sched_barrier(0);
    BWRITE(v0, 0);
    __builtin_amdgcn_sched_barrier(0);
    asm volatile("s_waitcnt vmcnt(0) lgkmcnt(0)" ::: "memory");
    __builtin_amdgcn_s_barrier();
    __builtin_amdgcn_sched_barrier(0);

    for (int t2 = 0; t2 < 16; t2 += 2) {
        if (t2 + 1 < 16) ASTAGE(1, t2 + 1);
        CLUSTER(0);
        __builtin_amdgcn_sched_barrier(0);
        if (t2 + 1 < 16) BWRITE(v1, 1);
        __builtin_amdgcn_sched_barrier(0);
        if (t2 + 2 < 16) {
            BLOAD(v0, t2 + 2);
            __builtin_amdgcn_sched_barrier(0);
            asm volatile("s_waitcnt vmcnt(32) lgkmcnt(0)" ::: "memory");
        } else {
            asm volatile("s_waitcnt vmcnt(0) lgkmcnt(0)" ::: "memory");
        }
        __builtin_amdgcn_s_barrier();
        __builtin_amdgcn_sched_barrier(0);

        {
            int t = t2 + 1;
            if (t + 1 < 16) ASTAGE(0, t + 1);
            CLUSTER(1);
            __builtin_amdgcn_sched_barrier(0);
            if (t + 1 < 16) {
                BWRITE(v0, 0);
                __builtin_amdgcn_sched_barrier(0);
                if (t + 2 < 16) {
                    BLOAD(v1, t + 2);
                    __builtin_amdgcn_sched_barrier(0);
                    asm volatile("s_waitcnt vmcnt(32) lgkmcnt(0)" ::: "memory");
                } else {
                    asm volatile("s_waitcnt vmcnt(0) lgkmcnt(0)" ::: "memory");
                }
                __builtin_amdgcn_s_barrier();
                __builtin_amdgcn_sched_barrier(0);
            }
        }
    }
#undef BLOAD
#undef BWRITE
#undef ASTAGE
#undef CLUSTER

#pragma unroll
    for (int mf = 0; mf < 2; mf++)
#pragma unroll
        for (int nf = 0; nf < 2; nf++) {
            int col = h0 + wn * 64 + nf * 32 + l31;
#pragma unroll
            for (int r = 0; r < 16; r++) {
                int rl = wm * 64 + mf * 32 + (r & 3) + 8 * (r >> 2) + 4 * lh;
                int gr = row0 + rl;
                if (gr < cntE) {
                    float w = wts[e * T_TOK + gr];
                    int t   = tok[e * T_TOK + gr];
                    atomicAdd(&out[(size_t)t * H_DIM + col], acc[mf][nf][r] * w);
                }
            }
        }
}

extern "C" void kernel_launch(void* const* d_in, const int* in_sizes, int n_in,
                              void* d_out, int out_size, void* d_ws, size_t ws_size,
                              hipStream_t stream)
{
    const float* x  = (const float*)d_in[0];
    const float* rw = (const float*)d_in[1];
    const float* wg = (const float*)d_in[2];
    const float* wu = (const float*)d_in[3];
    const float* wd = (const float*)d_in[4];
    float* out = (float*)d_out;

    char* ws = (char*)d_ws;
    int*   cnt       = (int*)(ws);
    int*   ntiles    = (int*)(ws + 32);
    int*   offs_pad  = (int*)(ws + 64);
    int*   tile_e    = (int*)(ws + 256);
    int*   tile_row0 = (int*)(ws + 512);
    int*   tok       = (int*)(ws + 64 * 1024);
    float* wts       = (float*)(ws + 128 * 1024);
    u16*   xbf       = (u16*)(ws + 256 * 1024);        // 4 MB
    u16*   act       = (u16*)(ws + 4608 * 1024);       // 20 MB
    u16*   gbuf      = (u16*)(ws + 26ull * 1024 * 1024); // 20 MB

    size_t need = 26ull * 1024 * 1024 + (size_t)MAX_SLOTS * I_DIM * 2;
    if (ws_size < need) return;

    hipMemsetAsync(cnt, 0, 32, stream);
    hipMemsetAsync(out, 0, (size_t)T_TOK * H_DIM * sizeof(float), stream);

    router_k<<<T_TOK / 4, 256, 0, stream>>>(x, rw, cnt, tok, wts, xbf);
    prefix_k<<<1, 64, 0, stream>>>(cnt, offs_pad, tile_e, tile_row0, ntiles);
    gu_k<0><<<NT_MAX * (I_DIM / 128), 256, 0, stream>>>(
        xbf, wg, cnt, offs_pad, tile_e, tile_row0, ntiles, tok, gbuf, act);
    gu_k<1><<<NT_MAX * (I_DIM / 128), 256, 0, stream>>>(
        xbf, wu, cnt, offs_pad, tile_e, tile_row0, ntiles, tok, gbuf, act);
    down_k<<<NT_MAX * (H_DIM / 128) * 2, 256, 0, stream>>>(
        act, wd, cnt, offs_pad, tile_e, tile_row0, ntiles, tok, wts, out);
}

// Round 12
// 205.597 us; speedup vs baseline: 1.4310x; 1.4310x over previous
//
#include <hip/hip_runtime.h>
#include <hip/hip_bf16.h>

#define T_TOK 2048
#define H_DIM 1024
#define E_N   8
#define I_DIM 2048
#define GW    4096        // gbuf row width (gate|up concat)

#define NT_MAX 40         // sum ceil(cnt_e/128) <= 4096/128 + 7 = 39
#define SLOTS  5120       // padded slot upper bound

typedef unsigned short u16;
typedef unsigned int   u32;
typedef __bf16 bf16_t;
typedef bf16_t bf16x8 __attribute__((ext_vector_type(8)));
typedef u16    u16x8  __attribute__((ext_vector_type(8)));
typedef u16    u16x4  __attribute__((ext_vector_type(4)));
typedef float  f32x16 __attribute__((ext_vector_type(16)));

#define MFMA32 __builtin_amdgcn_mfma_f32_32x32x16_bf16

__device__ __forceinline__ u16 bfbits(float f) {
    bf16_t b = (bf16_t)f;
    return __builtin_bit_cast(u16, b);
}
__device__ __forceinline__ float bf2f(u16 u) {
    u32 x = ((u32)u) << 16;
    return __builtin_bit_cast(float, x);
}

__device__ __forceinline__ void gload_lds16(const void* g, void* l) {
    __builtin_amdgcn_global_load_lds(
        (const __attribute__((address_space(1))) void*)g,
        (__attribute__((address_space(3))) void*)l, 16, 0, 0);
}

// B LDS tile: col n (0..127), k-slot kb (0..7)
__device__ __forceinline__ int tile_off(int n, int kb) {
    return n * 64 + ((kb ^ ((n >> 1) & 7)) << 3);
}
// A LDS tile (linear gload_lds dest, source k-group pre-XOR'd): row, kslot
__device__ __forceinline__ int a_off(int row, int kslot) {
    return row * 64 + ((kslot ^ (row & 7)) << 3);
}

// ---------------- router: 4 tokens/block; builds lists + inverse map
__global__ __launch_bounds__(256) void router_k(
    const float* __restrict__ x, const float* __restrict__ rw,
    int* __restrict__ cnt, int* __restrict__ tok,
    int4* __restrict__ invA, float2* __restrict__ invW,
    u16* __restrict__ xbf)
{
    int wid = threadIdx.x >> 6, lane = threadIdx.x & 63;
    int t = blockIdx.x * 4 + wid;
    const float* xr = x + (size_t)t * H_DIM;
    u16* xbr = xbf + (size_t)t * H_DIM;

    float acc[E_N];
#pragma unroll
    for (int e = 0; e < E_N; e++) acc[e] = 0.f;
    for (int j = 0; j < H_DIM / 64; j++) {
        float xv = xr[lane + 64 * j];
        xbr[lane + 64 * j] = bfbits(xv);
#pragma unroll
        for (int e = 0; e < E_N; e++)
            acc[e] += xv * rw[e * H_DIM + lane + 64 * j];
    }
#pragma unroll
    for (int e = 0; e < E_N; e++) {
        float v = acc[e];
        for (int off = 32; off; off >>= 1) v += __shfl_xor(v, off);
        acc[e] = v;
    }
    if (lane == 0) {
        int i0 = 0; float m0 = acc[0];
#pragma unroll
        for (int e = 1; e < E_N; e++) if (acc[e] > m0) { m0 = acc[e]; i0 = e; }
        int i1 = -1; float m1 = -INFINITY;
#pragma unroll
        for (int e = 0; e < E_N; e++) if (e != i0 && acc[e] > m1) { m1 = acc[e]; i1 = e; }
        float w0 = 1.f / (1.f + expf(m1 - m0));
        float w1 = 1.f - w0;
        int p0 = atomicAdd(&cnt[i0], 1);
        tok[i0 * T_TOK + p0] = t;
        int p1 = atomicAdd(&cnt[i1], 1);
        tok[i1 * T_TOK + p1] = t;
        invA[t] = make_int4(i0, p0, i1, p1);
        invW[t] = make_float2(w0, w1);
    }
}

// ---------------- prefix + padded tile map (BM=128)
__global__ void prefix_k(const int* __restrict__ cnt, int* __restrict__ offs_pad,
                         int* __restrict__ tile_e, int* __restrict__ tile_row0,
                         int* __restrict__ ntiles)
{
    if (threadIdx.x == 0) {
        int s = 0, nt = 0;
        for (int e = 0; e < E_N; e++) {
            offs_pad[e] = s;
            int c = cnt[e];
            int t = (c + 127) >> 7;
            for (int i = 0; i < t; i++) { tile_e[nt] = e; tile_row0[nt] = i * 128; nt++; }
            s += t * 128;
        }
        offs_pad[E_N] = s;
        *ntiles = nt;
    }
}

// ---------------- combined gate|up grouped GEMM (N = 4096 concat), fused cvt.
// tile 128x128, BK=64, 4 waves (2Mx2N), MFMA32, single-buffer 32KB LDS.
// Loop: ASTAGE -> BWRITE(v) -> syncthreads -> BLOAD(t+1) -> CLUSTER -> lgkm+s_barrier.
// B loads stay in flight across the raw barrier (absorbed at next BWRITE).
__global__ __launch_bounds__(256, 3) void gu_k(
    const u16* __restrict__ xbf, const float* __restrict__ wg, const float* __restrict__ wu,
    const int* __restrict__ cnt, const int* __restrict__ offs_pad,
    const int* __restrict__ tile_e, const int* __restrict__ tile_row0,
    const int* __restrict__ ntiles, const int* __restrict__ tok,
    u16* __restrict__ gbuf)
{
    int q = gridDim.x >> 3;
    int phys = blockIdx.x;
    int logical = (phys & 7) * q + (phys >> 3);
    int tb = logical % NT_MAX;
    int p  = logical / NT_MAX;             // n-panel 0..31 over GW=4096
    if (tb >= *ntiles) return;
    int e = tile_e[tb], row0 = tile_row0[tb];
    int cntE = cnt[e];
    int slot0 = offs_pad[e] + row0;
    int n0 = p * 128;
    int mat  = n0 >> 11;                   // 0: gate, 1: up
    int coln = n0 & 2047;

    __shared__ u16 AS[8192], BS[8192];     // 16 KB + 16 KB

    int tid = threadIdx.x;
    int lane = tid & 63, wid = tid >> 6;
    int wm = wid >> 1, wn = wid & 1;
    int l31 = lane & 31, lh = lane >> 5;

    const u16* asrc[4];
#pragma unroll
    for (int i = 0; i < 4; i++) {
        int row = (wid * 4 + i) * 8 + (lane >> 3);
        int rc = (row0 + row < cntE) ? (row0 + row) : (cntE - 1);
        asrc[i] = xbf + (size_t)tok[e * T_TOK + rc] * H_DIM
                  + (((lane & 7) ^ ((lane >> 3) & 7)) << 3);
    }
    int s0 = wid * 2048;

    int bn = tid & 127;
    int khalf = tid >> 7;                  // 0..1, 32 k's each
    const float* wsrc = (mat ? wu : wg) + (size_t)e * H_DIM * I_DIM + coln + bn;

    float v[32];

#define BLOAD(t) { \
    _Pragma("unroll") \
    for (int j = 0; j < 32; j++) \
        v[j] = wsrc[(size_t)((t) * 64 + khalf * 32 + j) * I_DIM]; }

#define BWRITE() { \
    _Pragma("unroll") \
    for (int jb = 0; jb < 4; jb++) { \
        u16x8 pk; \
        _Pragma("unroll") \
        for (int jj = 0; jj < 8; jj++) pk[jj] = bfbits(v[jb * 8 + jj]); \
        *reinterpret_cast<u16x8*>(&BS[tile_off(bn, khalf * 4 + jb)]) = pk; } }

#define ASTAGE(t) { \
    _Pragma("unroll") \
    for (int i = 0; i < 4; i++) \
        gload_lds16(asrc[i] + (size_t)(t) * 64, &AS[s0 + i * 512]); }

    f32x16 acc[2][2];
#pragma unroll
    for (int a = 0; a < 2; a++)
#pragma unroll
        for (int b = 0; b < 2; b++) acc[a][b] = (f32x16)0.f;

    BLOAD(0);
    for (int t = 0; t < 16; t++) {
        ASTAGE(t);
        BWRITE();                          // waits only the 32 B-load regs
        __syncthreads();                   // drains the 4 A gloads (B regs already consumed)
        if (t + 1 < 16) BLOAD(t + 1);      // in flight across cluster + barrier
#pragma unroll
        for (int ks = 0; ks < 4; ks++) {
            bf16x8 af[2], bfr[2];
#pragma unroll
            for (int mf = 0; mf < 2; mf++)
                af[mf] = *reinterpret_cast<const bf16x8*>(&AS[a_off(wm * 64 + mf * 32 + l31, ks * 2 + lh)]);
#pragma unroll
            for (int nf = 0; nf < 2; nf++)
                bfr[nf] = *reinterpret_cast<const bf16x8*>(&BS[tile_off(wn * 64 + nf * 32 + l31, ks * 2 + lh)]);
#pragma unroll
            for (int mf = 0; mf < 2; mf++)
#pragma unroll
                for (int nf = 0; nf < 2; nf++)
                    acc[mf][nf] = MFMA32(af[mf], bfr[nf], acc[mf][nf], 0, 0, 0);
        }
        asm volatile("s_waitcnt lgkmcnt(0)" ::: "memory");
        __builtin_amdgcn_s_barrier();      // raw: B loads stay outstanding
        __builtin_amdgcn_sched_barrier(0);
    }
#undef BLOAD
#undef BWRITE
#undef ASTAGE

    // epilogue: raw store (silu applied later by act_k); padded rows harmless
#pragma unroll
    for (int mf = 0; mf < 2; mf++)
#pragma unroll
        for (int nf = 0; nf < 2; nf++) {
            int col = n0 + wn * 64 + nf * 32 + l31;
#pragma unroll
            for (int r = 0; r < 16; r++) {
                int rl = wm * 64 + mf * 32 + (r & 3) + 8 * (r >> 2) + 4 * lh;
                gbuf[(size_t)(slot0 + rl) * GW + col] = bfbits(acc[mf][nf][r]);
            }
        }
}

// ---------------- act = silu(gate) * up, elementwise over all slots
__global__ __launch_bounds__(256) void act_k(const u16* __restrict__ gbuf,
                                             u16* __restrict__ act)
{
    int s = blockIdx.x;
    int i = threadIdx.x * 8;
    u16x8 g8 = *reinterpret_cast<const u16x8*>(&gbuf[(size_t)s * GW + i]);
    u16x8 u8 = *reinterpret_cast<const u16x8*>(&gbuf[(size_t)s * GW + 2048 + i]);
    u16x8 o;
#pragma unroll
    for (int j = 0; j < 8; j++) {
        float g = bf2f(g8[j]);
        float u = bf2f(u8[j]);
        o[j] = bfbits(g / (1.f + expf(-g)) * u);
    }
    *reinterpret_cast<u16x8*>(&act[(size_t)s * I_DIM + i]) = o;
}

// ---------------- down grouped GEMM: dbuf[kh][slot] = act @ w_down[e] (raw, no atomics)
__global__ __launch_bounds__(256, 3) void down_k(
    const u16* __restrict__ act, const float* __restrict__ wd,
    const int* __restrict__ cnt, const int* __restrict__ offs_pad,
    const int* __restrict__ tile_e, const int* __restrict__ tile_row0,
    const int* __restrict__ ntiles, const int* __restrict__ tok,
    u16* __restrict__ dbuf)
{
    int q = gridDim.x >> 3;
    int phys = blockIdx.x;
    int logical = (phys & 7) * q + (phys >> 3);
    int tb = logical % NT_MAX;
    int rest = logical / NT_MAX;
    int p  = rest & 7;                     // h-panel 0..7
    int kh = rest >> 3;                    // K half
    if (tb >= *ntiles) return;
    int e = tile_e[tb], row0 = tile_row0[tb];
    int slot0 = offs_pad[e] + row0;
    int h0 = p * 128;

    __shared__ u16 AS[8192], BS[8192];

    int tid = threadIdx.x;
    int lane = tid & 63, wid = tid >> 6;
    int wm = wid >> 1, wn = wid & 1;
    int l31 = lane & 31, lh = lane >> 5;

    const u16* asrc[4];
#pragma unroll
    for (int i = 0; i < 4; i++) {
        int row = (wid * 4 + i) * 8 + (lane >> 3);
        asrc[i] = act + (size_t)(slot0 + row) * I_DIM + kh * 1024
                  + (((lane & 7) ^ ((lane >> 3) & 7)) << 3);
    }
    int s0 = wid * 2048;

    int bn = tid & 127;
    int khalf = tid >> 7;
    const float* dsrc = wd + ((size_t)e * I_DIM + kh * 1024) * H_DIM + h0 + bn;

    float v[32];

#define BLOAD(t) { \
    _Pragma("unroll") \
    for (int j = 0; j < 32; j++) \
        v[j] = dsrc[(size_t)((t) * 64 + khalf * 32 + j) * H_DIM]; }

#define BWRITE() { \
    _Pragma("unroll") \
    for (int jb = 0; jb < 4; jb++) { \
        u16x8 pk; \
        _Pragma("unroll") \
        for (int jj = 0; jj < 8; jj++) pk[jj] = bfbits(v[jb * 8 + jj]); \
        *reinterpret_cast<u16x8*>(&BS[tile_off(bn, khalf * 4 + jb)]) = pk; } }

#define ASTAGE(t) { \
    _Pragma("unroll") \
    for (int i = 0; i < 4; i++) \
        gload_lds16(asrc[i] + (size_t)(t) * 64, &AS[s0 + i * 512]); }

    f32x16 acc[2][2];
#pragma unroll
    for (int a = 0; a < 2; a++)
#pragma unroll
        for (int b = 0; b < 2; b++) acc[a][b] = (f32x16)0.f;

    BLOAD(0);
    for (int t = 0; t < 16; t++) {
        ASTAGE(t);
        BWRITE();
        __syncthreads();
        if (t + 1 < 16) BLOAD(t + 1);
#pragma unroll
        for (int ks = 0; ks < 4; ks++) {
            bf16x8 af[2], bfr[2];
#pragma unroll
            for (int mf = 0; mf < 2; mf++)
                af[mf] = *reinterpret_cast<const bf16x8*>(&AS[a_off(wm * 64 + mf * 32 + l31, ks * 2 + lh)]);
#pragma unroll
            for (int nf = 0; nf < 2; nf++)
                bfr[nf] = *reinterpret_cast<const bf16x8*>(&BS[tile_off(wn * 64 + nf * 32 + l31, ks * 2 + lh)]);
#pragma unroll
            for (int mf = 0; mf < 2; mf++)
#pragma unroll
                for (int nf = 0; nf < 2; nf++)
                    acc[mf][nf] = MFMA32(af[mf], bfr[nf], acc[mf][nf], 0, 0, 0);
        }
        asm volatile("s_waitcnt lgkmcnt(0)" ::: "memory");
        __builtin_amdgcn_s_barrier();
        __builtin_amdgcn_sched_barrier(0);
    }
#undef BLOAD
#undef BWRITE
#undef ASTAGE

#pragma unroll
    for (int mf = 0; mf < 2; mf++)
#pragma unroll
        for (int nf = 0; nf < 2; nf++) {
            int col = h0 + wn * 64 + nf * 32 + l31;
#pragma unroll
            for (int r = 0; r < 16; r++) {
                int rl = wm * 64 + mf * 32 + (r & 3) + 8 * (r >> 2) + 4 * lh;
                dbuf[(size_t)(kh * SLOTS + slot0 + rl) * H_DIM + col] = bfbits(acc[mf][nf][r]);
            }
        }
}

// ---------------- gather: out[t][h] = w0*(d[kh0][s0]+d[kh1][s0]) + w1*(...s1)
__global__ __launch_bounds__(256) void gather_k(
    const u16* __restrict__ dbuf, const int4* __restrict__ invA,
    const float2* __restrict__ invW, const int* __restrict__ offs_pad,
    float* __restrict__ out)
{
    int t = blockIdx.x;
    int h = threadIdx.x * 4;
    int4 ia = invA[t];
    float2 w = invW[t];
    int s0 = offs_pad[ia.x] + ia.y;
    int s1 = offs_pad[ia.z] + ia.w;

    u16x4 a0 = *reinterpret_cast<const u16x4*>(&dbuf[(size_t)s0 * H_DIM + h]);
    u16x4 a1 = *reinterpret_cast<const u16x4*>(&dbuf[(size_t)(SLOTS + s0) * H_DIM + h]);
    u16x4 b0 = *reinterpret_cast<const u16x4*>(&dbuf[(size_t)s1 * H_DIM + h]);
    u16x4 b1 = *reinterpret_cast<const u16x4*>(&dbuf[(size_t)(SLOTS + s1) * H_DIM + h]);

    float4 o;
    float* op = &o.x;
#pragma unroll
    for (int j = 0; j < 4; j++)
        op[j] = w.x * (bf2f(a0[j]) + bf2f(a1[j])) + w.y * (bf2f(b0[j]) + bf2f(b1[j]));
    *reinterpret_cast<float4*>(&out[(size_t)t * H_DIM + h]) = o;
}

extern "C" void kernel_launch(void* const* d_in, const int* in_sizes, int n_in,
                              void* d_out, int out_size, void* d_ws, size_t ws_size,
                              hipStream_t stream)
{
    const float* x  = (const float*)d_in[0];
    const float* rw = (const float*)d_in[1];
    const float* wg = (const float*)d_in[2];
    const float* wu = (const float*)d_in[3];
    const float* wd = (const float*)d_in[4];
    float* out = (float*)d_out;

    char* ws = (char*)d_ws;
    int*    cnt       = (int*)(ws);
    int*    ntiles    = (int*)(ws + 32);
    int*    offs_pad  = (int*)(ws + 64);
    int*    tile_e    = (int*)(ws + 256);
    int*    tile_row0 = (int*)(ws + 512);
    int*    tok       = (int*)(ws + 64 * 1024);            // 64 KB
    int4*   invA      = (int4*)(ws + 160 * 1024);          // 32 KB
    float2* invW      = (float2*)(ws + 200 * 1024);        // 16 KB
    u16*    xbf       = (u16*)(ws + 256 * 1024);           // 4 MB
    u16*    act       = (u16*)(ws + 5ull * 1024 * 1024);   // 20 MB
    u16*    gbuf      = (u16*)(ws + 26ull * 1024 * 1024);  // 40 MB
    u16*    dbuf      = (u16*)(ws + 67ull * 1024 * 1024);  // 20 MB

    size_t need = 88ull * 1024 * 1024;
    if (ws_size < need) return;

    hipMemsetAsync(cnt, 0, 32, stream);

    router_k<<<T_TOK / 4, 256, 0, stream>>>(x, rw, cnt, tok, invA, invW, xbf);
    prefix_k<<<1, 64, 0, stream>>>(cnt, offs_pad, tile_e, tile_row0, ntiles);
    gu_k<<<NT_MAX * (GW / 128), 256, 0, stream>>>(
        xbf, wg, wu, cnt, offs_pad, tile_e, tile_row0, ntiles, tok, gbuf);
    act_k<<<SLOTS, 256, 0, stream>>>(gbuf, act);
    down_k<<<NT_MAX * (H_DIM / 128) * 2, 256, 0, stream>>>(
        act, wd, cnt, offs_pad, tile_e, tile_row0, ntiles, tok, dbuf);
    gather_k<<<T_TOK, 256, 0, stream>>>(dbuf, invA, invW, offs_pad, out);
}